// Round 12
// baseline (6308.992 us; speedup 1.0000x reference)
//
#include <hip/hip_runtime.h>
#include <hip/hip_bf16.h>

// LSTM: T=8192, IN=3000, H=100 (4H=400), torch gate order i,f,g,o.
// Phase 1: xg[T][400] = input @ w_ih^T + (b_ih+b_hh), PERMUTED cols (4u+g).
// Phase 2: single-workgroup scan, 256 threads / 4 waves, VALU dot2 engine.
// ROUND-12 REDESIGN vs R8-R11 (MFMA, ~1400 cyc/step, 3 scheduling nulls):
//   a 16x16x32 MFMA costs ~16-19 cyc/SIMD; 28/wave = ~500 cyc matrix-pipe
//   occupancy with 96% waste (matvec uses 1 of 16 B columns). VALU dot2 does
//   the same matvec in 208 instr = 416 cyc/SIMD with zero waste.
//   - lane pair owns unit u: even lane = rows (i_u, f_u), odd = (g_u, o_u)
//   - weights in PHYSICAL AGPRs a0..a103 (R8-proven v_accvgpr_write pinning),
//     per-use v_accvgpr_read (documented) + v_dot2_f32_f16, 2 dep chains
//   - gate exchange: ONE ds_swizzle xor-1 (no barrier, no select chain)
//   - unified nonlinearity t = 1 - kk*rcp(exp(kk*g)+1): kk=1 sigmoid (even),
//     kk=2 tanh (odd) -> divergence-free
//   - xg folded into accumulator init; depth-4 named prefetch; raw
//     lgkmcnt-only barrier (1 per step)

#define GBM 128
#define GBN 128
#define GBK 16

typedef _Float16 h2_t  __attribute__((ext_vector_type(2)));
typedef float    f32x4 __attribute__((ext_vector_type(4)));

__global__ __launch_bounds__(256) void gates_gemm(
    const float* __restrict__ A,    // [T][IN]
    const float* __restrict__ W,    // [FH][IN]
    const float* __restrict__ bih,  // [FH]
    const float* __restrict__ bhh,  // [FH]
    float* __restrict__ XG,         // [T][FH]  (permuted columns)
    int T, int IN, int FH)
{
    __shared__ __align__(16) float As[GBK][GBM];
    __shared__ __align__(16) float Bs[GBK][GBN];
    const int bm = blockIdx.x * GBM;
    const int bn = blockIdx.y * GBN;
    const int tid = (int)threadIdx.x;
    const int tx = tid & 15, ty = tid >> 4;
    const int H = FH >> 2;   // 100

    float acc[8][8];
    #pragma unroll
    for (int i = 0; i < 8; ++i)
        #pragma unroll
        for (int j = 0; j < 8; ++j) acc[i][j] = 0.f;

    for (int k0 = 0; k0 < IN; k0 += GBK) {
        __syncthreads();
        #pragma unroll
        for (int q = 0; q < 2; ++q) {
            int idx = tid + q * 256;
            int row = idx >> 2;
            int kq  = (idx & 3) << 2;
            int gk  = k0 + kq;
            float4 av = make_float4(0.f, 0.f, 0.f, 0.f);
            float4 bv = make_float4(0.f, 0.f, 0.f, 0.f);
            if (gk < IN) {
                av = *(const float4*)&A[(size_t)(bm + row) * IN + gk];
                if (bn + row < FH)
                    bv = *(const float4*)&W[(size_t)(bn + row) * IN + gk];
            }
            As[kq + 0][row] = av.x; As[kq + 1][row] = av.y;
            As[kq + 2][row] = av.z; As[kq + 3][row] = av.w;
            Bs[kq + 0][row] = bv.x; Bs[kq + 1][row] = bv.y;
            Bs[kq + 2][row] = bv.z; Bs[kq + 3][row] = bv.w;
        }
        __syncthreads();
        #pragma unroll
        for (int kk = 0; kk < GBK; ++kk) {
            float4 a0 = *(const float4*)&As[kk][ty * 4];
            float4 a1 = *(const float4*)&As[kk][64 + ty * 4];
            float4 b0 = *(const float4*)&Bs[kk][tx * 4];
            float4 b1 = *(const float4*)&Bs[kk][64 + tx * 4];
            float am[8] = {a0.x, a0.y, a0.z, a0.w, a1.x, a1.y, a1.z, a1.w};
            float bn_[8] = {b0.x, b0.y, b0.z, b0.w, b1.x, b1.y, b1.z, b1.w};
            #pragma unroll
            for (int i = 0; i < 8; ++i)
                #pragma unroll
                for (int j = 0; j < 8; ++j)
                    acc[i][j] = fmaf(am[i], bn_[j], acc[i][j]);
        }
    }

    #pragma unroll
    for (int i = 0; i < 8; ++i) {
        int r = bm + ((i < 4) ? (ty * 4 + i) : (64 + ty * 4 + (i - 4)));
        #pragma unroll
        for (int j = 0; j < 8; ++j) {
            int cidx = bn + ((j < 4) ? (tx * 4 + j) : (64 + tx * 4 + (j - 4)));
            if (cidx < FH) {
                int pc = 4 * (cidx % H) + cidx / H;   // unit-major permutation
                XG[(size_t)r * FH + pc] = acc[i][j] + bih[cidx] + bhh[cidx];
            }
        }
    }
}

// pack W[k], W[k+1] (f32) into one dword of two f16 (zero past K=100)
__device__ __forceinline__ float pack_pair(const float* rp, int k) {
    float a = 0.f, b = 0.f;
    if (k < 100) { a = rp[k]; b = rp[k + 1]; }
    h2_t p = {(_Float16)a, (_Float16)b};
    return __builtin_bit_cast(float, p);
}

#define WRW(N, V) \
    asm volatile("v_accvgpr_write_b32 a" #N ", %0" :: "v"(V) : "a" #N)

// one weight-pair step for both gate chains:
//   g0 += w0[j] . h[j]   (weight from AGPR N0)
//   g1 += w1[j] . h[j]   (weight from AGPR N1)
#define D2(N0, N1, HV) { float t0_, t1_; \
    asm volatile("v_accvgpr_read_b32 %1, a" #N0 "\n\t" \
                 "v_accvgpr_read_b32 %2, a" #N1 "\n\t" \
                 "v_dot2_f32_f16 %0, %1, %4, %0\n\t" \
                 "v_dot2_f32_f16 %3, %2, %4, %3" \
                 : "+v"(g0), "=&v"(t0_), "=&v"(t1_), "+v"(g1) : "v"(HV)); }

// raw barrier: orders LDS (lgkmcnt) but leaves global loads in flight
#define BAR() asm volatile("s_waitcnt lgkmcnt(0)\n\ts_barrier" ::: "memory")

__global__ __launch_bounds__(256, 1) void lstm_scan_dot2(
    const float* __restrict__ XGp,   // [T][400] permuted (4u+g)
    const float* __restrict__ Whh,   // [400][100] original layout
    const float* __restrict__ wlin,  // [100]
    const float* __restrict__ blin,  // [1]
    float* __restrict__ out, int T)
{
    __shared__ __align__(16) _Float16 hbuf[2][104];  // 208B per buffer
    __shared__ float hfin[100];
    const int tid    = (int)threadIdx.x;
    const int parity = tid & 1;          // 0: gates i,f   1: gates g,o
    const int p      = tid >> 1;         // unit index (pair id)
    const int pc     = (p < 100) ? p : 99;
    const bool act   = (parity == 0) && (p < 100);
    const float kk   = 1.f + (float)parity;   // 1 -> sigmoid, 2 -> tanh

    // weight rows: even = (u, u+100) = (i,f); odd = (u+200, u+300) = (g,o)
    const float* r0p = Whh + (size_t)(pc + parity * 200) * 100;
    const float* r1p = Whh + (size_t)(pc + 100 + parity * 200) * 100;

    // ---- load 2x52 packed-f16 weight dwords into PHYSICAL AGPRs ----
#define LW(j, N0, N1) { WRW(N0, pack_pair(r0p, 2*(j))); \
                        WRW(N1, pack_pair(r1p, 2*(j))); }
    LW(0,0,52)   LW(1,1,53)   LW(2,2,54)   LW(3,3,55)   LW(4,4,56)
    LW(5,5,57)   LW(6,6,58)   LW(7,7,59)   LW(8,8,60)   LW(9,9,61)
    LW(10,10,62) LW(11,11,63) LW(12,12,64) LW(13,13,65) LW(14,14,66)
    LW(15,15,67) LW(16,16,68) LW(17,17,69) LW(18,18,70) LW(19,19,71)
    LW(20,20,72) LW(21,21,73) LW(22,22,74) LW(23,23,75) LW(24,24,76)
    LW(25,25,77) LW(26,26,78) LW(27,27,79) LW(28,28,80) LW(29,29,81)
    LW(30,30,82) LW(31,31,83) LW(32,32,84) LW(33,33,85) LW(34,34,86)
    LW(35,35,87) LW(36,36,88) LW(37,37,89) LW(38,38,90) LW(39,39,91)
    LW(40,40,92) LW(41,41,93) LW(42,42,94) LW(43,43,95) LW(44,44,96)
    LW(45,45,97) LW(46,46,98) LW(47,47,99) LW(48,48,100) LW(49,49,101)
    LW(50,50,102) LW(51,51,103)
#undef LW

    if (tid < 104) { hbuf[0][tid] = (_Float16)0.f; hbuf[1][tid] = (_Float16)0.f; }

    // xg: even lane needs permuted cols (4u, 4u+1); odd (4u+2, 4u+3)
    const int xoff = 4 * pc + 2 * parity;
#define XR(i) (*(const float2*)(XGp + (size_t)((i) < T ? (i) : (T - 1)) * 400 + xoff))

    // depth-4 prefetch: four NAMED registers (never rotated)
    float2 xa = XR(0), xb = XR(1), xc = XR(2), xd = XR(3);

    float c = 0.f, hlast = 0.f;
    int cur = 0;
    BAR();

#define SUBSTEP(XP, TNEXT) { \
    float2 xnew_ = XR(TNEXT); \
    const f32x4* h4 = (const f32x4*)hbuf[cur]; \
    f32x4 hA = h4[0], hB = h4[1], hC = h4[2], hD = h4[3]; \
    f32x4 hE = h4[4], hF = h4[5], hG = h4[6], hH = h4[7]; \
    f32x4 hI = h4[8], hJ = h4[9], hK = h4[10], hL = h4[11], hM = h4[12]; \
    float g0 = XP.x, g1 = XP.y; \
    D2(0,52,hA.x)   D2(1,53,hA.y)   D2(2,54,hA.z)   D2(3,55,hA.w) \
    D2(4,56,hB.x)   D2(5,57,hB.y)   D2(6,58,hB.z)   D2(7,59,hB.w) \
    D2(8,60,hC.x)   D2(9,61,hC.y)   D2(10,62,hC.z)  D2(11,63,hC.w) \
    D2(12,64,hD.x)  D2(13,65,hD.y)  D2(14,66,hD.z)  D2(15,67,hD.w) \
    D2(16,68,hE.x)  D2(17,69,hE.y)  D2(18,70,hE.z)  D2(19,71,hE.w) \
    D2(20,72,hF.x)  D2(21,73,hF.y)  D2(22,74,hF.z)  D2(23,75,hF.w) \
    D2(24,76,hG.x)  D2(25,77,hG.y)  D2(26,78,hG.z)  D2(27,79,hG.w) \
    D2(28,80,hH.x)  D2(29,81,hH.y)  D2(30,82,hH.z)  D2(31,83,hH.w) \
    D2(32,84,hI.x)  D2(33,85,hI.y)  D2(34,86,hI.z)  D2(35,87,hI.w) \
    D2(36,88,hJ.x)  D2(37,89,hJ.y)  D2(38,90,hJ.z)  D2(39,91,hJ.w) \
    D2(40,92,hK.x)  D2(41,93,hK.y)  D2(42,94,hK.z)  D2(43,95,hK.w) \
    D2(44,96,hL.x)  D2(45,97,hL.y)  D2(46,98,hL.z)  D2(47,99,hL.w) \
    D2(48,100,hM.x) D2(49,101,hM.y) D2(50,102,hM.z) D2(51,103,hM.w) \
    /* unified nonlinearity: even->sigmoid(g0)=iv, odd->tanh(g0)=gv */ \
    float e0  = __expf(kk * g0); \
    float t0v = 1.f - kk * __builtin_amdgcn_rcpf(e0 + 1.f); \
    float e1  = __expf(-g1); \
    float t1v = __builtin_amdgcn_rcpf(1.f + e1);   /* s(gf) / s(go) */ \
    /* exchange with partner lane (xor 1), wait fused into same asm */ \
    float rg_, ro_; \
    asm volatile("ds_swizzle_b32 %0, %2 offset:0x041F\n\t" \
                 "ds_swizzle_b32 %1, %3 offset:0x041F\n\t" \
                 "s_waitcnt lgkmcnt(0)" \
                 : "=&v"(rg_), "=&v"(ro_) : "v"(t0v), "v"(t1v)); \
    c = fmaf(t1v, c, t0v * rg_);          /* fv*c + iv*gv  (even lanes) */ \
    float e2 = __expf(2.f * c); \
    float th = 1.f - 2.f * __builtin_amdgcn_rcpf(e2 + 1.f); \
    float hv_ = ro_ * th;                 /* ov * tanh(c) */ \
    if (act) { hlast = hv_; hbuf[cur ^ 1][p] = (_Float16)hv_; } \
    BAR(); \
    cur ^= 1; \
    XP = xnew_; }

    for (int t = 0; t < T; t += 4) {
        SUBSTEP(xa, t + 4)
        SUBSTEP(xb, t + 5)
        SUBSTEP(xc, t + 6)
        SUBSTEP(xd, t + 7)
    }
#undef SUBSTEP
#undef XR

    if (act) hfin[p] = hlast * wlin[p];
    __syncthreads();
    if (tid == 0) {
        float s = blin[0];
        for (int k = 0; k < 100; ++k) s += hfin[k];
        out[0] = s;
    }
}

extern "C" void kernel_launch(void* const* d_in, const int* in_sizes, int n_in,
                              void* d_out, int out_size, void* d_ws, size_t ws_size,
                              hipStream_t stream) {
    const float* input = (const float*)d_in[0];  // [T][IN]
    const float* w_ih  = (const float*)d_in[1];  // [4H][IN]
    const float* w_hh  = (const float*)d_in[2];  // [4H][H]
    const float* b_ih  = (const float*)d_in[3];  // [4H]
    const float* b_hh  = (const float*)d_in[4];  // [4H]
    const float* w_lin = (const float*)d_in[5];  // [H]
    const float* b_lin = (const float*)d_in[6];  // [1]
    float* out = (float*)d_out;

    const int FH = in_sizes[3];            // 400
    const int IN = in_sizes[1] / FH;       // 3000
    const int T  = in_sizes[0] / IN;       // 8192

    float* xg = (float*)d_ws;              // [T][FH] = 13.1 MB (permuted)

    dim3 grid((T + GBM - 1) / GBM, (FH + GBN - 1) / GBN);
    gates_gemm<<<grid, 256, 0, stream>>>(input, w_ih, b_ih, b_hh, xg, T, IN, FH);
    lstm_scan_dot2<<<1, 256, 0, stream>>>(xg, w_hh, w_lin, b_lin, out, T);
}